// Round 1
// baseline (104.784 us; speedup 1.0000x reference)
//
#include <hip/hip_runtime.h>
#include <math.h>

#define IW 256
#define IH 256
#define NG 1000
#define ALPHA_MAX 0.999f

// One block per image row (256 threads = 256 pixels, coalesced store).
// Per-gaussian params are precomputed cooperatively into LDS once per block:
//   p0[n] = (cx, cy, A, B), p1[n] = (C, opac, color, 0)
// where exponent(dx,dy) = A*dx^2 + B*dx*dy + C*dy^2  (the -0.5 and the
// inverse-covariance are folded into A,B,C).
__global__ __launch_bounds__(256) void splat2d_kernel(
    const float* __restrict__ means,     // N x 2
    const float* __restrict__ quats,     // N
    const float* __restrict__ scales,    // N x 2
    const float* __restrict__ rgbs,      // N x 1
    const float* __restrict__ opacities, // N
    float* __restrict__ out)             // 1 x 1 x H x W
{
    __shared__ float4 p0[NG];
    __shared__ float4 p1[NG];

    const int tid = threadIdx.x;

    // Cooperative per-gaussian param precompute (4 gaussians/thread).
    for (int n = tid; n < NG; n += 256) {
        float cx = means[2 * n + 0];
        float cy = means[2 * n + 1];
        float q  = quats[n];
        float sx = scales[2 * n + 0];
        float sy = scales[2 * n + 1];
        float cq = cosf(q), sq = sinf(q);
        float sx2 = sx * sx, sy2 = sy * sy;
        float a11 = cq * cq * sx2 + sq * sq * sy2;
        float a12 = cq * sq * (sx2 - sy2);
        float a22 = sq * sq * sx2 + cq * cq * sy2;
        float det = a11 * a22 - a12 * a12;
        float inv = 1.0f / det;
        float A  = -0.5f * a22 * inv;
        float B  =          a12 * inv;   // = -(-a12/det), folded with -0.5*2
        float Cc = -0.5f * a11 * inv;
        float op  = 1.0f / (1.0f + expf(-opacities[n]));
        float col = 1.0f / (1.0f + expf(-rgbs[n]));
        p0[n] = make_float4(cx, cy, A, B);
        p1[n] = make_float4(Cc, op, col, 0.0f);
    }
    __syncthreads();

    const float px = (float)tid + 0.5f;
    const float py = (float)blockIdx.x + 0.5f;

    float T = 1.0f;
    float accum = 0.0f;

    // NG = 1000 = 125 * 8; unroll by 8, wave-uniform early exit between chunks.
    for (int n0 = 0; n0 < NG; n0 += 8) {
        #pragma unroll
        for (int k = 0; k < 8; ++k) {
            const int n = n0 + k;
            float4 q0 = p0[n];
            float4 q1 = p1[n];
            float dx = px - q0.x;
            float dy = py - q0.y;
            float e = (q0.z * dx + q0.w * dy) * dx + q1.x * dy * dy;
            float alpha = q1.y * __expf(e);
            alpha = fminf(alpha, ALPHA_MAX);
            accum = fmaf(alpha * T, q1.z, accum);
            T = fmaf(-alpha, T, T);
        }
        if (__all(T < 1e-5f)) break;
    }

    out[blockIdx.x * IW + tid] = accum;
}

extern "C" void kernel_launch(void* const* d_in, const int* in_sizes, int n_in,
                              void* d_out, int out_size, void* d_ws, size_t ws_size,
                              hipStream_t stream) {
    const float* means     = (const float*)d_in[0];
    const float* quats     = (const float*)d_in[1];
    const float* scales    = (const float*)d_in[2];
    const float* rgbs      = (const float*)d_in[3];
    const float* opacities = (const float*)d_in[4];
    float* out = (float*)d_out;

    splat2d_kernel<<<IH, IW, 0, stream>>>(means, quats, scales, rgbs, opacities, out);
}

// Round 2
// 89.465 us; speedup vs baseline: 1.1712x; 1.1712x over previous
//
#include <hip/hip_runtime.h>
#include <math.h>

#define IW 256
#define IH 256
#define NG 1000
#define NSEG 8
#define SEG (NG / NSEG)   // 125
#define ALPHA_MAX 0.999f

// Segment kernel: block (y, s) composites gaussians [s*SEG, (s+1)*SEG) for
// row y, writing partial (color, transmittance) per pixel to workspace.
// Params for the segment are computed in-block into LDS (125 gaussians, 4KB).
__global__ __launch_bounds__(256) void splat2d_segment_kernel(
    const float* __restrict__ means,     // N x 2
    const float* __restrict__ quats,     // N
    const float* __restrict__ scales,    // N x 2
    const float* __restrict__ rgbs,      // N x 1
    const float* __restrict__ opacities, // N
    float2* __restrict__ segout)         // NSEG x H x W
{
    __shared__ float4 p0[SEG];  // cx, cy, A, B
    __shared__ float4 p1[SEG];  // C, opac, color, 0

    const int tid = threadIdx.x;
    const int y   = blockIdx.x;
    const int s   = blockIdx.y;
    const int n0g = s * SEG;

    if (tid < SEG) {
        int n = n0g + tid;
        float cx = means[2 * n + 0];
        float cy = means[2 * n + 1];
        float q  = quats[n];
        float sx = scales[2 * n + 0];
        float sy = scales[2 * n + 1];
        float cq = cosf(q), sq = sinf(q);
        float sx2 = sx * sx, sy2 = sy * sy;
        float a11 = cq * cq * sx2 + sq * sq * sy2;
        float a12 = cq * sq * (sx2 - sy2);
        float a22 = sq * sq * sx2 + cq * cq * sy2;
        float det = a11 * a22 - a12 * a12;
        float inv = 1.0f / det;
        float A  = -0.5f * a22 * inv;
        float B  =          a12 * inv;
        float Cc = -0.5f * a11 * inv;
        float op  = 1.0f / (1.0f + expf(-opacities[n]));
        float col = 1.0f / (1.0f + expf(-rgbs[n]));
        p0[tid] = make_float4(cx, cy, A, B);
        p1[tid] = make_float4(Cc, op, col, 0.0f);
    }
    __syncthreads();

    const float px = (float)tid + 0.5f;
    const float py = (float)y + 0.5f;

    float T = 1.0f;
    float accum = 0.0f;

    #pragma unroll 5
    for (int k = 0; k < SEG; ++k) {
        float4 q0 = p0[k];
        float4 q1 = p1[k];
        float dx = px - q0.x;
        float dy = py - q0.y;
        float t  = fmaf(q0.w, dy, q0.z * dx);       // A*dx + B*dy
        float e  = fmaf(t, dx, q1.x * dy * dy);     // + C*dy^2
        float alpha = q1.y * __expf(e);
        alpha = fminf(alpha, ALPHA_MAX);
        accum = fmaf(alpha * T, q1.z, accum);
        T = fmaf(-alpha, T, T);
    }

    segout[(s * IH + y) * IW + tid] = make_float2(accum, T);
}

// Combine kernel: per pixel, fold the NSEG (c, T) partials in order.
__global__ __launch_bounds__(256) void splat2d_combine_kernel(
    const float2* __restrict__ segout,   // NSEG x H x W
    float* __restrict__ out)             // 1 x 1 x H x W
{
    const int pix = blockIdx.x * 256 + threadIdx.x;

    float c = 0.0f;
    float T = 1.0f;
    #pragma unroll
    for (int s = 0; s < NSEG; ++s) {
        float2 v = segout[s * (IH * IW) + pix];
        c = fmaf(T, v.x, c);
        T *= v.y;
    }
    out[pix] = c;
}

extern "C" void kernel_launch(void* const* d_in, const int* in_sizes, int n_in,
                              void* d_out, int out_size, void* d_ws, size_t ws_size,
                              hipStream_t stream) {
    const float* means     = (const float*)d_in[0];
    const float* quats     = (const float*)d_in[1];
    const float* scales    = (const float*)d_in[2];
    const float* rgbs      = (const float*)d_in[3];
    const float* opacities = (const float*)d_in[4];
    float* out = (float*)d_out;
    float2* segout = (float2*)d_ws;   // NSEG*IH*IW float2 = 4 MiB

    splat2d_segment_kernel<<<dim3(IH, NSEG), 256, 0, stream>>>(
        means, quats, scales, rgbs, opacities, segout);
    splat2d_combine_kernel<<<(IH * IW) / 256, 256, 0, stream>>>(segout, out);
}